// Round 8
// baseline (130.968 us; speedup 1.0000x reference)
//
#include <hip/hip_runtime.h>
#include <hip/hip_bf16.h>
#include <stdint.h>

#define N_PTS   4096
#define M_CODES 4096
#define ZDIM    1024
#define KG      (ZDIM / 8)          // 128 k-groups of 8 elements
// Tiled bf16 layout: elem (r,k) at ((rb*KG + kg)*16 + r16)*8 + ke
//   rb=r>>4, r16=r&15, kg=k>>3, ke=k&7. Chunk (rb,kg) = 16 rows x 8 k = 256 B.

typedef __attribute__((ext_vector_type(8))) short bf16x8;
typedef __attribute__((ext_vector_type(4))) float f32x4;

__device__ __forceinline__ unsigned short f2bf(float f) {
    __hip_bfloat16 h = __float2bfloat16(f);
    return *reinterpret_cast<unsigned short*>(&h);
}
__device__ __forceinline__ unsigned enc_f32(float f) {
    unsigned u = __float_as_uint(f);
    return (u & 0x80000000u) ? ~u : (u | 0x80000000u);
}
__device__ __forceinline__ float dec_f32(unsigned e) {
    unsigned u = (e & 0x80000000u) ? (e ^ 0x80000000u) : ~e;
    return __uint_as_float(u);
}

// ---------------------------------------------------------------------------
// prep: fp32 -> bf16 + TILED layout + row sum-of-squares.
// One block = 16 rows of one matrix (rb block). grid 512 (256 z + 256 e).
// Phase 1: coalesced row loads, convert, in-LDS [row][k] tile (padded rows),
//          fp32 row sums via wave shuffles.
// Phase 2: read LDS transposed as 16 B chunks, store one CONTIGUOUS 32 KB
//          tiled segment (lane-linear stores).
// ---------------------------------------------------------------------------
#define PREP_PITCH 1032   // ushorts per LDS row: 1024 + 8 pad (16 B-aligned)
__global__ __launch_bounds__(256) void prep_kernel(
    const float* __restrict__ z, const float* __restrict__ e,
    unsigned short* __restrict__ zb, unsigned short* __restrict__ eb,
    float* __restrict__ zsq, float* __restrict__ esq,
    unsigned* __restrict__ min_enc) {
    __shared__ unsigned short tile[16 * PREP_PITCH];  // ~33 KB
    __shared__ float redbuf[16 * 4];

    const int t = threadIdx.x;
    const int b = blockIdx.x;
    if (b < 16) min_enc[b * 256 + t] = 0xFFFFFFFFu;

    const bool is_z = b < 256;
    const int rb = b & 255;
    const float* src = (is_z ? z : e) + (size_t)rb * 16 * ZDIM;
    unsigned short* dst = (is_z ? zb : eb) + (size_t)rb * 16384;  // 32 KB seg
    const int w = t >> 6, lane = t & 63;

    // Phase 1: row "it" handled by all 256 threads (256 float4 = 1024 elems)
    #pragma unroll
    for (int it = 0; it < 16; it++) {
        float4 v = reinterpret_cast<const float4*>(src + (size_t)it * ZDIM)[t];
        ushort4 o;
        o.x = f2bf(v.x); o.y = f2bf(v.y); o.z = f2bf(v.z); o.w = f2bf(v.w);
        *reinterpret_cast<ushort4*>(&tile[it * PREP_PITCH + t * 4]) = o;
        float s = v.x * v.x + v.y * v.y + v.z * v.z + v.w * v.w;
        #pragma unroll
        for (int off = 1; off < 64; off <<= 1) s += __shfl_xor(s, off, 64);
        if (lane == 0) redbuf[it * 4 + w] = s;
    }
    __syncthreads();

    // Phase 2: chunk c = kg*16 + r16 -> dst + c*8 ushorts (fully linear)
    #pragma unroll
    for (int it2 = 0; it2 < 8; it2++) {
        const int c = it2 * 256 + t;          // 0..2047
        const int kg = c >> 4, r16 = c & 15;
        bf16x8 val = *reinterpret_cast<const bf16x8*>(
            &tile[r16 * PREP_PITCH + kg * 8]);
        *reinterpret_cast<bf16x8*>(&dst[(size_t)c * 8]) = val;
    }
    if (t < 16) {
        float sq = redbuf[t * 4] + redbuf[t * 4 + 1] +
                   redbuf[t * 4 + 2] + redbuf[t * 4 + 3];
        const int row = rb * 16 + t;
        if (is_z) zsq[row] = sq; else esq[row] = sq;
    }
}

// ---------------------------------------------------------------------------
// gemm_min: 128x128 block tile, 2 waves (128 thr), wave tile 64x128
// (acc[4][8]). K-stage = 64 (8 kgroups) staged via 16 x global_load_lds of
// 2 KB straight runs from the tiled layout; fragments then read with
// ds_read_b128 at base + lane*16 (lane-linear -> conflict-free, m134 pattern).
// 64 MFMA per barrier pair. reads/MFMA = 0.375 (was 0.5).
// No fences, no done-counter (R4/R7 lessons). grid (32,32).
// ---------------------------------------------------------------------------
__global__ __launch_bounds__(128) void gemm_min_kernel(
    const unsigned short* __restrict__ zb, const unsigned short* __restrict__ eb,
    const float* __restrict__ zsq, unsigned* __restrict__ min_enc) {
    __shared__ __align__(16) unsigned short As[8192];  // 16 KB: [rb'8][kg'8][r16][8]
    __shared__ __align__(16) unsigned short Bs[8192];  // 16 KB
    __shared__ float zsq_s[128];
    __shared__ float colmin[2][128];

    const int t = threadIdx.x;        // 0..127
    const int bx = blockIdx.x;        // code (col) block
    const int by = blockIdx.y;        // point (row) block
    const int lane = t & 63;
    const int w = t >> 6;             // wave = wm (0..1)
    const int lrow = lane & 15;
    const int q = lane >> 4;

    zsq_s[t] = zsq[by * 128 + t];

    f32x4 acc[4][8];
    #pragma unroll
    for (int i = 0; i < 4; i++)
        #pragma unroll
        for (int j = 0; j < 8; j++) acc[i][j] = (f32x4){0.f, 0.f, 0.f, 0.f};

    for (int kg0 = 0; kg0 < KG; kg0 += 8) {   // 16 stages of K=64
        #pragma unroll
        for (int j = 0; j < 8; j++) {
            // A row-block by*8+j: 2 KB straight run (kg' 0..7 x r16 0..15)
            const unsigned short* ga =
                zb + (size_t)(by * 8 + j) * 16384 + kg0 * 128 + t * 8;
            const unsigned short* gb =
                eb + (size_t)(bx * 8 + j) * 16384 + kg0 * 128 + t * 8;
            __builtin_amdgcn_global_load_lds(
                (const __attribute__((address_space(1))) void*)ga,
                (__attribute__((address_space(3))) void*)(As + j * 1024 + w * 512),
                16, 0, 0);
            __builtin_amdgcn_global_load_lds(
                (const __attribute__((address_space(1))) void*)gb,
                (__attribute__((address_space(3))) void*)(Bs + j * 1024 + w * 512),
                16, 0, 0);
        }
        __syncthreads();

        #pragma unroll
        for (int s = 0; s < 2; s++) {   // two K=32 slices
            bf16x8 a[4], bb[8];
            #pragma unroll
            for (int am = 0; am < 4; am++)
                a[am] = *(const bf16x8*)(As + (w * 4 + am) * 1024 + s * 512 + lane * 8);
            #pragma unroll
            for (int an = 0; an < 8; an++)
                bb[an] = *(const bf16x8*)(Bs + an * 1024 + s * 512 + lane * 8);
            #pragma unroll
            for (int am = 0; am < 4; am++)
                #pragma unroll
                for (int an = 0; an < 8; an++)
                    acc[am][an] = __builtin_amdgcn_mfma_f32_16x16x32_bf16(
                        a[am], bb[an], acc[am][an], 0, 0, 0);
        }
        __syncthreads();
    }

    // Epilogue. C/D layout: row = q*4+r (within am tile), col = lrow.
    #pragma unroll
    for (int an = 0; an < 8; an++) {
        float v = 3.4e38f;
        #pragma unroll
        for (int am = 0; am < 4; am++) {
            const int rbase = w * 64 + am * 16 + q * 4;
            f32x4 c = acc[am][an];
            v = fminf(v, zsq_s[rbase + 0] - 2.f * c[0]);
            v = fminf(v, zsq_s[rbase + 1] - 2.f * c[1]);
            v = fminf(v, zsq_s[rbase + 2] - 2.f * c[2]);
            v = fminf(v, zsq_s[rbase + 3] - 2.f * c[3]);
        }
        v = fminf(v, __shfl_xor(v, 16, 64));
        v = fminf(v, __shfl_xor(v, 32, 64));
        if (q == 0) colmin[w][an * 16 + lrow] = v;
    }
    __syncthreads();
    {
        const float m = fminf(colmin[0][t], colmin[1][t]);
        atomicMin(&min_enc[bx * 128 + t], enc_f32(m));
    }
}

// ---------------------------------------------------------------------------
// finalize: mean_j (dec(min_enc[j]) + esq[j]) -> single fp32 scalar.
// ---------------------------------------------------------------------------
__global__ __launch_bounds__(256) void finalize_kernel(
    const unsigned* __restrict__ min_enc, const float* __restrict__ esq,
    float* __restrict__ out) {
    const int t = threadIdx.x;
    float s = 0.f;
    #pragma unroll
    for (int i = 0; i < M_CODES / 256; i++) {
        const int j = i * 256 + t;
        s += dec_f32(min_enc[j]) + esq[j];
    }
    #pragma unroll
    for (int off = 1; off < 64; off <<= 1) s += __shfl_xor(s, off, 64);
    __shared__ float red[4];
    if ((t & 63) == 0) red[t >> 6] = s;
    __syncthreads();
    if (t == 0) out[0] = (red[0] + red[1] + red[2] + red[3]) * (1.f / M_CODES);
}

extern "C" void kernel_launch(void* const* d_in, const int* in_sizes, int n_in,
                              void* d_out, int out_size, void* d_ws, size_t ws_size,
                              hipStream_t stream) {
    (void)in_sizes; (void)n_in; (void)out_size; (void)ws_size;
    const float* z = (const float*)d_in[0];
    const float* e = (const float*)d_in[1];
    char* ws = (char*)d_ws;
    unsigned short* zb = (unsigned short*)ws;                            // 8 MB
    unsigned short* eb = (unsigned short*)(ws + ((size_t)8 << 20));      // 8 MB
    float* zsq = (float*)(ws + ((size_t)16 << 20));                      // 16 KB
    float* esq = (float*)(ws + ((size_t)16 << 20) + 16384);              // 16 KB
    unsigned* min_enc = (unsigned*)(ws + ((size_t)16 << 20) + 32768);    // 16 KB

    prep_kernel<<<dim3(512), dim3(256), 0, stream>>>(
        z, e, zb, eb, zsq, esq, min_enc);
    gemm_min_kernel<<<dim3(32, 32), dim3(128), 0, stream>>>(
        zb, eb, zsq, min_enc);
    finalize_kernel<<<dim3(1), dim3(256), 0, stream>>>(min_enc, esq, (float*)d_out);
}

// Round 9
// 119.978 us; speedup vs baseline: 1.0916x; 1.0916x over previous
//
#include <hip/hip_runtime.h>
#include <hip/hip_bf16.h>
#include <stdint.h>

#define N_PTS   4096
#define M_CODES 4096
#define ZDIM    1024
#define KG      (ZDIM / 8)          // 128 k-groups of 8 elements
// Tiled bf16 layout: elem (r,k) at seg(rb)*16384 + kg*128 + r16*8 + ke
//   rb=r>>4, r16=r&15, kg=k>>3, ke=k&7. Chunk (rb,kg) = 16 rows x 8 k = 256 B.

typedef __attribute__((ext_vector_type(8))) short bf16x8;
typedef __attribute__((ext_vector_type(4))) float f32x4;

__device__ __forceinline__ unsigned short f2bf(float f) {
    __hip_bfloat16 h = __float2bfloat16(f);
    return *reinterpret_cast<unsigned short*>(&h);
}
__device__ __forceinline__ unsigned enc_f32(float f) {
    unsigned u = __float_as_uint(f);
    return (u & 0x80000000u) ? ~u : (u | 0x80000000u);
}
__device__ __forceinline__ float dec_f32(unsigned e) {
    unsigned u = (e & 0x80000000u) ? (e ^ 0x80000000u) : ~e;
    return __uint_as_float(u);
}

// ---------------------------------------------------------------------------
// prep: fp32 -> bf16 + TILED layout + row sum-of-squares (R8-proven).
// ---------------------------------------------------------------------------
#define PREP_PITCH 1032   // ushorts per LDS row: 1024 + 8 pad (16 B-aligned)
__global__ __launch_bounds__(256) void prep_kernel(
    const float* __restrict__ z, const float* __restrict__ e,
    unsigned short* __restrict__ zb, unsigned short* __restrict__ eb,
    float* __restrict__ zsq, float* __restrict__ esq,
    unsigned* __restrict__ min_enc) {
    __shared__ unsigned short tile[16 * PREP_PITCH];  // ~33 KB
    __shared__ float redbuf[16 * 4];

    const int t = threadIdx.x;
    const int b = blockIdx.x;
    if (b < 16) min_enc[b * 256 + t] = 0xFFFFFFFFu;

    const bool is_z = b < 256;
    const int rb = b & 255;
    const float* src = (is_z ? z : e) + (size_t)rb * 16 * ZDIM;
    unsigned short* dst = (is_z ? zb : eb) + (size_t)rb * 16384;  // 32 KB seg
    const int w = t >> 6, lane = t & 63;

    #pragma unroll
    for (int it = 0; it < 16; it++) {
        float4 v = reinterpret_cast<const float4*>(src + (size_t)it * ZDIM)[t];
        ushort4 o;
        o.x = f2bf(v.x); o.y = f2bf(v.y); o.z = f2bf(v.z); o.w = f2bf(v.w);
        *reinterpret_cast<ushort4*>(&tile[it * PREP_PITCH + t * 4]) = o;
        float s = v.x * v.x + v.y * v.y + v.z * v.z + v.w * v.w;
        #pragma unroll
        for (int off = 1; off < 64; off <<= 1) s += __shfl_xor(s, off, 64);
        if (lane == 0) redbuf[it * 4 + w] = s;
    }
    __syncthreads();

    #pragma unroll
    for (int it2 = 0; it2 < 8; it2++) {
        const int c = it2 * 256 + t;          // 0..2047
        const int kg = c >> 4, r16 = c & 15;
        bf16x8 val = *reinterpret_cast<const bf16x8*>(
            &tile[r16 * PREP_PITCH + kg * 8]);
        *reinterpret_cast<bf16x8*>(&dst[(size_t)c * 8]) = val;
    }
    if (t < 16) {
        float sq = redbuf[t * 4] + redbuf[t * 4 + 1] +
                   redbuf[t * 4 + 2] + redbuf[t * 4 + 3];
        const int row = rb * 16 + t;
        if (is_z) zsq[row] = sq; else esq[row] = sq;
    }
}

// ---------------------------------------------------------------------------
// gemm_min: R6 occupancy (256 thr, 4 waves 2x2 of 64x64, 4 blocks/CU,
// 16 waves/CU) + R8 conflict-free tiled fragments (ds_read_b128 at
// base + lane*16B). K-stage 64, 8 global_load_lds of 4 KB per stage,
// 32 MFMA per barrier per wave. grid (32,32).
// LDS As/Bs layout: [rb' 0..7][kg' 0..7][r16][ke] = rb'*1024 + kg'*128
// + r16*8 + ke (elements).
// ---------------------------------------------------------------------------
__global__ __launch_bounds__(256) void gemm_min_kernel(
    const unsigned short* __restrict__ zb, const unsigned short* __restrict__ eb,
    const float* __restrict__ zsq, unsigned* __restrict__ min_enc) {
    __shared__ __align__(16) unsigned short As[8192];  // 16 KB
    __shared__ __align__(16) unsigned short Bs[8192];  // 16 KB
    __shared__ float zsq_s[128];
    __shared__ float colmin[2][128];

    const int t = threadIdx.x;        // 0..255
    const int bx = blockIdx.x;        // code (col) block
    const int by = blockIdx.y;        // point (row) block
    const int lane = t & 63;
    const int w = t >> 6;             // 0..3
    const int wm = w >> 1, wn = w & 1;
    const int lrow = lane & 15;
    const int q = lane >> 4;

    if (t < 128) zsq_s[t] = zsq[by * 128 + t];

    f32x4 acc[4][4];
    #pragma unroll
    for (int i = 0; i < 4; i++)
        #pragma unroll
        for (int j = 0; j < 4; j++) acc[i][j] = (f32x4){0.f, 0.f, 0.f, 0.f};

    // staging: instr j covers 4 KB = 2 rb-chunks' 8-kgroup runs (2 KB each).
    // thread t: seg = base + j*2 + (t>>7); inner elem = kg0*128 + (t&127)*8.
    // LDS dest: As + j*2048 + w*512 (wave-uniform) + lane*8.
    const int seg_half = t >> 7;            // 0..1
    const int inner = (t & 127) * 8;        // element offset in 2 KB run
    const int lds_w = w * 512;              // wave-uniform (elements)

    for (int kg0 = 0; kg0 < KG; kg0 += 8) {   // 16 stages of K=64
        #pragma unroll
        for (int j = 0; j < 4; j++) {
            const unsigned short* ga =
                zb + (size_t)(by * 8 + j * 2 + seg_half) * 16384 + kg0 * 128 + inner;
            const unsigned short* gb =
                eb + (size_t)(bx * 8 + j * 2 + seg_half) * 16384 + kg0 * 128 + inner;
            __builtin_amdgcn_global_load_lds(
                (const __attribute__((address_space(1))) void*)ga,
                (__attribute__((address_space(3))) void*)(As + j * 2048 + lds_w),
                16, 0, 0);
            __builtin_amdgcn_global_load_lds(
                (const __attribute__((address_space(1))) void*)gb,
                (__attribute__((address_space(3))) void*)(Bs + j * 2048 + lds_w),
                16, 0, 0);
        }
        __syncthreads();

        #pragma unroll
        for (int s = 0; s < 2; s++) {   // two K=32 slices
            bf16x8 a[4], bb[4];
            #pragma unroll
            for (int am = 0; am < 4; am++)
                a[am] = *(const bf16x8*)(As + (wm * 4 + am) * 1024 + s * 512 + lane * 8);
            #pragma unroll
            for (int an = 0; an < 4; an++)
                bb[an] = *(const bf16x8*)(Bs + (wn * 4 + an) * 1024 + s * 512 + lane * 8);
            #pragma unroll
            for (int am = 0; am < 4; am++)
                #pragma unroll
                for (int an = 0; an < 4; an++)
                    acc[am][an] = __builtin_amdgcn_mfma_f32_16x16x32_bf16(
                        a[am], bb[an], acc[am][an], 0, 0, 0);
        }
        __syncthreads();
    }

    // Epilogue (R5/R6-proven). C/D layout: row = q*4+r, col = lrow.
    #pragma unroll
    for (int an = 0; an < 4; an++) {
        float v = 3.4e38f;
        #pragma unroll
        for (int am = 0; am < 4; am++) {
            const int rbase = wm * 64 + am * 16 + q * 4;
            f32x4 c = acc[am][an];
            v = fminf(v, zsq_s[rbase + 0] - 2.f * c[0]);
            v = fminf(v, zsq_s[rbase + 1] - 2.f * c[1]);
            v = fminf(v, zsq_s[rbase + 2] - 2.f * c[2]);
            v = fminf(v, zsq_s[rbase + 3] - 2.f * c[3]);
        }
        v = fminf(v, __shfl_xor(v, 16, 64));
        v = fminf(v, __shfl_xor(v, 32, 64));
        if (q == 0) colmin[wm][wn * 64 + an * 16 + lrow] = v;
    }
    __syncthreads();
    if (t < 128) {
        const float m = fminf(colmin[0][t], colmin[1][t]);
        atomicMin(&min_enc[bx * 128 + t], enc_f32(m));
    }
}

// ---------------------------------------------------------------------------
// finalize: mean_j (dec(min_enc[j]) + esq[j]) -> single fp32 scalar.
// ---------------------------------------------------------------------------
__global__ __launch_bounds__(256) void finalize_kernel(
    const unsigned* __restrict__ min_enc, const float* __restrict__ esq,
    float* __restrict__ out) {
    const int t = threadIdx.x;
    float s = 0.f;
    #pragma unroll
    for (int i = 0; i < M_CODES / 256; i++) {
        const int j = i * 256 + t;
        s += dec_f32(min_enc[j]) + esq[j];
    }
    #pragma unroll
    for (int off = 1; off < 64; off <<= 1) s += __shfl_xor(s, off, 64);
    __shared__ float red[4];
    if ((t & 63) == 0) red[t >> 6] = s;
    __syncthreads();
    if (t == 0) out[0] = (red[0] + red[1] + red[2] + red[3]) * (1.f / M_CODES);
}

extern "C" void kernel_launch(void* const* d_in, const int* in_sizes, int n_in,
                              void* d_out, int out_size, void* d_ws, size_t ws_size,
                              hipStream_t stream) {
    (void)in_sizes; (void)n_in; (void)out_size; (void)ws_size;
    const float* z = (const float*)d_in[0];
    const float* e = (const float*)d_in[1];
    char* ws = (char*)d_ws;
    unsigned short* zb = (unsigned short*)ws;                            // 8 MB
    unsigned short* eb = (unsigned short*)(ws + ((size_t)8 << 20));      // 8 MB
    float* zsq = (float*)(ws + ((size_t)16 << 20));                      // 16 KB
    float* esq = (float*)(ws + ((size_t)16 << 20) + 16384);              // 16 KB
    unsigned* min_enc = (unsigned*)(ws + ((size_t)16 << 20) + 32768);    // 16 KB

    prep_kernel<<<dim3(512), dim3(256), 0, stream>>>(
        z, e, zb, eb, zsq, esq, min_enc);
    gemm_min_kernel<<<dim3(32, 32), dim3(256), 0, stream>>>(
        zb, eb, zsq, min_enc);
    finalize_kernel<<<dim3(1), dim3(256), 0, stream>>>(min_enc, esq, (float*)d_out);
}

// Round 10
// 113.783 us; speedup vs baseline: 1.1510x; 1.0545x over previous
//
#include <hip/hip_runtime.h>
#include <hip/hip_bf16.h>
#include <stdint.h>

#define N_PTS   4096
#define M_CODES 4096
#define ZDIM    1024
#define KG      (ZDIM / 8)          // 128 k-groups of 8 elements
// Tiled bf16 layout: elem (r,k) at seg(rb)*16384 + kg*128 + r16*8 + ke
//   rb=r>>4, r16=r&15, kg=k>>3, ke=k&7. Chunk (rb,kg) = 16 rows x 8 k = 256 B.

typedef __attribute__((ext_vector_type(8))) short bf16x8;
typedef __attribute__((ext_vector_type(4))) float f32x4;

__device__ __forceinline__ unsigned short f2bf(float f) {
    __hip_bfloat16 h = __float2bfloat16(f);
    return *reinterpret_cast<unsigned short*>(&h);
}
__device__ __forceinline__ unsigned enc_f32(float f) {
    unsigned u = __float_as_uint(f);
    return (u & 0x80000000u) ? ~u : (u | 0x80000000u);
}
__device__ __forceinline__ float dec_f32(unsigned e) {
    unsigned u = (e & 0x80000000u) ? (e ^ 0x80000000u) : ~e;
    return __uint_as_float(u);
}

// ---------------------------------------------------------------------------
// prep: fp32 -> bf16 + TILED layout + row sum-of-squares (R8-proven,
// unchanged).
// ---------------------------------------------------------------------------
#define PREP_PITCH 1032   // ushorts per LDS row: 1024 + 8 pad (16 B-aligned)
__global__ __launch_bounds__(256) void prep_kernel(
    const float* __restrict__ z, const float* __restrict__ e,
    unsigned short* __restrict__ zb, unsigned short* __restrict__ eb,
    float* __restrict__ zsq, float* __restrict__ esq,
    unsigned* __restrict__ min_enc) {
    __shared__ unsigned short tile[16 * PREP_PITCH];  // ~33 KB
    __shared__ float redbuf[16 * 4];

    const int t = threadIdx.x;
    const int b = blockIdx.x;
    if (b < 16) min_enc[b * 256 + t] = 0xFFFFFFFFu;

    const bool is_z = b < 256;
    const int rb = b & 255;
    const float* src = (is_z ? z : e) + (size_t)rb * 16 * ZDIM;
    unsigned short* dst = (is_z ? zb : eb) + (size_t)rb * 16384;  // 32 KB seg
    const int w = t >> 6, lane = t & 63;

    #pragma unroll
    for (int it = 0; it < 16; it++) {
        float4 v = reinterpret_cast<const float4*>(src + (size_t)it * ZDIM)[t];
        ushort4 o;
        o.x = f2bf(v.x); o.y = f2bf(v.y); o.z = f2bf(v.z); o.w = f2bf(v.w);
        *reinterpret_cast<ushort4*>(&tile[it * PREP_PITCH + t * 4]) = o;
        float s = v.x * v.x + v.y * v.y + v.z * v.z + v.w * v.w;
        #pragma unroll
        for (int off = 1; off < 64; off <<= 1) s += __shfl_xor(s, off, 64);
        if (lane == 0) redbuf[it * 4 + w] = s;
    }
    __syncthreads();

    #pragma unroll
    for (int it2 = 0; it2 < 8; it2++) {
        const int c = it2 * 256 + t;          // 0..2047
        const int kg = c >> 4, r16 = c & 15;
        bf16x8 val = *reinterpret_cast<const bf16x8*>(
            &tile[r16 * PREP_PITCH + kg * 8]);
        *reinterpret_cast<bf16x8*>(&dst[(size_t)c * 8]) = val;
    }
    if (t < 16) {
        float sq = redbuf[t * 4] + redbuf[t * 4 + 1] +
                   redbuf[t * 4 + 2] + redbuf[t * 4 + 3];
        const int row = rb * 16 + t;
        if (is_z) zsq[row] = sq; else esq[row] = sq;
    }
}

// ---------------------------------------------------------------------------
// gemm_min: A through LDS (shared across wn waves), B DIRECT from global
// into registers — the tiled layout makes each B fragment a contiguous,
// perfectly-coalesced 1 KB wave read (lane addr = cb*16384 + kg*128 +
// lrow*8, lane-linear). Halves LDS-pipe traffic; B data rides the
// otherwise-idle VMEM-return path (L1/L2-served, overlaps MFMA).
// 256 thr = 4 waves (2x2 of 64x64), K-stage 64, grid (32,32).
// __launch_bounds__(256,4) pins VGPR<=128 for 4 blocks/CU.
// ---------------------------------------------------------------------------
__global__ __launch_bounds__(256, 4) void gemm_min_kernel(
    const unsigned short* __restrict__ zb, const unsigned short* __restrict__ eb,
    const float* __restrict__ zsq, unsigned* __restrict__ min_enc) {
    __shared__ __align__(16) unsigned short As[8192];  // 16 KB
    __shared__ float zsq_s[128];
    __shared__ float colmin[2][128];

    const int t = threadIdx.x;        // 0..255
    const int bx = blockIdx.x;        // code (col) block
    const int by = blockIdx.y;        // point (row) block
    const int lane = t & 63;
    const int w = t >> 6;             // 0..3
    const int wm = w >> 1, wn = w & 1;
    const int lrow = lane & 15;
    const int q = lane >> 4;

    if (t < 128) zsq_s[t] = zsq[by * 128 + t];

    f32x4 acc[4][4];
    #pragma unroll
    for (int i = 0; i < 4; i++)
        #pragma unroll
        for (int j = 0; j < 4; j++) acc[i][j] = (f32x4){0.f, 0.f, 0.f, 0.f};

    // A staging: instr j covers 4 KB = 2 rb-chunks' 8-kgroup runs.
    const int seg_half = t >> 7;            // 0..1
    const int inner = (t & 127) * 8;        // element offset in 2 KB run
    const int lds_w = w * 512;              // wave-uniform (elements)

    // B fragment base: cb chunks bx*8 + wn*4 + an; lane offset q*128+lrow*8
    // = lane*8 (lane-linear 1 KB run per fragment).
    const unsigned short* b_base =
        eb + (size_t)(bx * 8 + wn * 4) * 16384 + lane * 8;

    for (int kg0 = 0; kg0 < KG; kg0 += 8) {   // 16 stages of K=64
        #pragma unroll
        for (int j = 0; j < 4; j++) {
            const unsigned short* ga =
                zb + (size_t)(by * 8 + j * 2 + seg_half) * 16384 + kg0 * 128 + inner;
            __builtin_amdgcn_global_load_lds(
                (const __attribute__((address_space(1))) void*)ga,
                (__attribute__((address_space(3))) void*)(As + j * 2048 + lds_w),
                16, 0, 0);
        }
        __syncthreads();

        #pragma unroll
        for (int s = 0; s < 2; s++) {   // two K=32 slices
            bf16x8 a[4], bb[4];
            #pragma unroll
            for (int an = 0; an < 4; an++)
                bb[an] = *(const bf16x8*)(b_base + (size_t)an * 16384 +
                                          kg0 * 128 + s * 512);
            #pragma unroll
            for (int am = 0; am < 4; am++)
                a[am] = *(const bf16x8*)(As + (wm * 4 + am) * 1024 + s * 512 + lane * 8);
            #pragma unroll
            for (int am = 0; am < 4; am++)
                #pragma unroll
                for (int an = 0; an < 4; an++)
                    acc[am][an] = __builtin_amdgcn_mfma_f32_16x16x32_bf16(
                        a[am], bb[an], acc[am][an], 0, 0, 0);
        }
        __syncthreads();
    }

    // Epilogue (R5/R6-proven). C/D layout: row = q*4+r, col = lrow.
    #pragma unroll
    for (int an = 0; an < 4; an++) {
        float v = 3.4e38f;
        #pragma unroll
        for (int am = 0; am < 4; am++) {
            const int rbase = wm * 64 + am * 16 + q * 4;
            f32x4 c = acc[am][an];
            v = fminf(v, zsq_s[rbase + 0] - 2.f * c[0]);
            v = fminf(v, zsq_s[rbase + 1] - 2.f * c[1]);
            v = fminf(v, zsq_s[rbase + 2] - 2.f * c[2]);
            v = fminf(v, zsq_s[rbase + 3] - 2.f * c[3]);
        }
        v = fminf(v, __shfl_xor(v, 16, 64));
        v = fminf(v, __shfl_xor(v, 32, 64));
        if (q == 0) colmin[wm][wn * 64 + an * 16 + lrow] = v;
    }
    __syncthreads();
    if (t < 128) {
        const float m = fminf(colmin[0][t], colmin[1][t]);
        atomicMin(&min_enc[bx * 128 + t], enc_f32(m));
    }
}

// ---------------------------------------------------------------------------
// finalize: mean_j (dec(min_enc[j]) + esq[j]) -> single fp32 scalar.
// ---------------------------------------------------------------------------
__global__ __launch_bounds__(256) void finalize_kernel(
    const unsigned* __restrict__ min_enc, const float* __restrict__ esq,
    float* __restrict__ out) {
    const int t = threadIdx.x;
    float s = 0.f;
    #pragma unroll
    for (int i = 0; i < M_CODES / 256; i++) {
        const int j = i * 256 + t;
        s += dec_f32(min_enc[j]) + esq[j];
    }
    #pragma unroll
    for (int off = 1; off < 64; off <<= 1) s += __shfl_xor(s, off, 64);
    __shared__ float red[4];
    if ((t & 63) == 0) red[t >> 6] = s;
    __syncthreads();
    if (t == 0) out[0] = (red[0] + red[1] + red[2] + red[3]) * (1.f / M_CODES);
}

extern "C" void kernel_launch(void* const* d_in, const int* in_sizes, int n_in,
                              void* d_out, int out_size, void* d_ws, size_t ws_size,
                              hipStream_t stream) {
    (void)in_sizes; (void)n_in; (void)out_size; (void)ws_size;
    const float* z = (const float*)d_in[0];
    const float* e = (const float*)d_in[1];
    char* ws = (char*)d_ws;
    unsigned short* zb = (unsigned short*)ws;                            // 8 MB
    unsigned short* eb = (unsigned short*)(ws + ((size_t)8 << 20));      // 8 MB
    float* zsq = (float*)(ws + ((size_t)16 << 20));                      // 16 KB
    float* esq = (float*)(ws + ((size_t)16 << 20) + 16384);              // 16 KB
    unsigned* min_enc = (unsigned*)(ws + ((size_t)16 << 20) + 32768);    // 16 KB

    prep_kernel<<<dim3(512), dim3(256), 0, stream>>>(
        z, e, zb, eb, zsq, esq, min_enc);
    gemm_min_kernel<<<dim3(32, 32), dim3(256), 0, stream>>>(
        zb, eb, zsq, min_enc);
    finalize_kernel<<<dim3(1), dim3(256), 0, stream>>>(min_enc, esq, (float*)d_out);
}